// Round 5
// baseline (175.780 us; speedup 1.0000x reference)
//
#include <hip/hip_runtime.h>

#define BH  64
#define SEQ 4096
#define DH  64

// ---------------------------------------------------------------------------
// Kernel 1: partial kv = k^T v over a chunk of S rows. One (b,h,chunk)/block.
// No LDS: per row each thread loads k[r][d0:d0+4] (1 float4) and v[r][e0:e0+8]
// (2 float4) straight to registers. Duplicate lane addresses merge in the
// coalescer; rows stream linearly so HBM lines are fully consumed.
// 128 threads, thread tile 4(d) x 8(e): 32 FMA per 3 loads per row.
// ---------------------------------------------------------------------------
__global__ __launch_bounds__(128, 3) void kv_partial_kernel(
    const float* __restrict__ k, const float* __restrict__ v,
    float* __restrict__ partial, int nchunk, int rows_per_chunk) {
  const int t = threadIdx.x;
  const int bh = blockIdx.x / nchunk;
  const int chunk = blockIdx.x - bh * nchunk;

  const float* kb = k + (size_t)bh * SEQ * DH + (size_t)chunk * rows_per_chunk * DH;
  const float* vb = v + (size_t)bh * SEQ * DH + (size_t)chunk * rows_per_chunk * DH;

  const int d0 = (t & 15) * 4;   // 16 d-groups of 4
  const int e0 = (t >> 4) * 8;   // 8 e-groups of 8

  float acc[4][8];
#pragma unroll
  for (int i = 0; i < 4; ++i)
#pragma unroll
    for (int j = 0; j < 8; ++j) acc[i][j] = 0.f;

#pragma unroll 2
  for (int r0 = 0; r0 < rows_per_chunk; r0 += 4) {
    float4 ka[4], va0[4], va1[4];
#pragma unroll
    for (int rr = 0; rr < 4; ++rr) {
      const float* kr = kb + (size_t)(r0 + rr) * DH;
      const float* vr = vb + (size_t)(r0 + rr) * DH;
      ka[rr]  = *(const float4*)(kr + d0);
      va0[rr] = *(const float4*)(vr + e0);
      va1[rr] = *(const float4*)(vr + e0 + 4);
    }
#pragma unroll
    for (int rr = 0; rr < 4; ++rr) {
      float kaa[4] = {ka[rr].x, ka[rr].y, ka[rr].z, ka[rr].w};
      float vaa[8] = {va0[rr].x, va0[rr].y, va0[rr].z, va0[rr].w,
                      va1[rr].x, va1[rr].y, va1[rr].z, va1[rr].w};
#pragma unroll
      for (int i = 0; i < 4; ++i)
#pragma unroll
        for (int j = 0; j < 8; ++j) acc[i][j] += kaa[i] * vaa[j];
    }
  }

  float* pb = partial + (size_t)blockIdx.x * (DH * DH);
#pragma unroll
  for (int i = 0; i < 4; ++i) {
    float4 w0 = {acc[i][0], acc[i][1], acc[i][2], acc[i][3]};
    float4 w1 = {acc[i][4], acc[i][5], acc[i][6], acc[i][7]};
    *(float4*)&pb[(d0 + i) * 64 + e0]     = w0;
    *(float4*)&pb[(d0 + i) * 64 + e0 + 4] = w1;
  }
}

// ---------------------------------------------------------------------------
// Kernel 2: reduce partials -> kvf [BH][64*64]. Fully coalesced float4.
// Grid: 256 blocks x 256 threads covers 65536 float4 slots.
// ---------------------------------------------------------------------------
__global__ __launch_bounds__(256) void kv_reduce_kernel(
    const float* __restrict__ partial, float* __restrict__ kvf, int nchunk) {
  const int gid = blockIdx.x * 256 + threadIdx.x;
  const int bh = gid >> 10;
  const int idx = gid & 1023;
  float4 s = {0.f, 0.f, 0.f, 0.f};
  for (int c = 0; c < nchunk; ++c) {
    const float4* p = (const float4*)(partial + ((size_t)bh * nchunk + c) * (DH * DH));
    float4 x = p[idx];
    s.x += x.x; s.y += x.y; s.z += x.z; s.w += x.w;
  }
  ((float4*)kvf)[gid] = s;
}

// ---------------------------------------------------------------------------
// Kernel 3: out = q @ kv. kv staged in LDS (16 KB, broadcast reads).
// Thread: 4 rows (stride 64) x 16 cols; q direct global->reg in 4-d chunks.
// Fully unrolled d-chunks (static component select) so q loads pipeline
// ahead of the FMA stream. __launch_bounds__(256,4): ~111 live VGPR -> fits
// 128-reg budget, 16 waves/CU.
// ---------------------------------------------------------------------------
__global__ __launch_bounds__(256, 4) void out_kernel(
    const float* __restrict__ q, const float* __restrict__ kvf,
    float* __restrict__ out) {
  const int t = threadIdx.x;
  const int bh = blockIdx.x >> 4;
  const int rb = blockIdx.x & 15;
  const int row_base = rb * 256;

  __shared__ float kv_lds[64 * 64];

  // stage kv (16 KB = 1024 float4), coalesced
  const float4* gkv4 = (const float4*)(kvf + (size_t)bh * (DH * DH));
  float4* kv4 = (float4*)kv_lds;
#pragma unroll
  for (int j = 0; j < 4; ++j) kv4[t + j * 256] = gkv4[t + j * 256];
  __syncthreads();

  const int r0 = t >> 2;          // 0..63; rows r0 + 64*ri
  const int c0 = (t & 3) * 16;    // 4 col-groups of 16

  const float* qb = q + (size_t)bh * SEQ * DH + (size_t)(row_base + r0) * DH;

  float acc[4][16];
#pragma unroll
  for (int i = 0; i < 4; ++i)
#pragma unroll
    for (int j = 0; j < 16; ++j) acc[i][j] = 0.f;

#pragma unroll 4
  for (int ds = 0; ds < 16; ++ds) {
    const int d0 = ds * 4;
    float4 qv[4];
#pragma unroll
    for (int ri = 0; ri < 4; ++ri)
      qv[ri] = *(const float4*)&qb[ri * 64 * DH + d0];
    // static scalarization (no dynamic .x/.y/.z/.w select)
    float qf[4][4];
#pragma unroll
    for (int ri = 0; ri < 4; ++ri) {
      qf[ri][0] = qv[ri].x; qf[ri][1] = qv[ri].y;
      qf[ri][2] = qv[ri].z; qf[ri][3] = qv[ri].w;
    }
#pragma unroll
    for (int dd = 0; dd < 4; ++dd) {
      const float* kr = &kv_lds[(d0 + dd) * DH + c0];
      float4 k0 = *(const float4*)&kr[0];
      float4 k1 = *(const float4*)&kr[4];
      float4 k2 = *(const float4*)&kr[8];
      float4 k3 = *(const float4*)&kr[12];
#pragma unroll
      for (int ri = 0; ri < 4; ++ri) {
        const float qs = qf[ri][dd];
        acc[ri][0]  += qs * k0.x; acc[ri][1]  += qs * k0.y;
        acc[ri][2]  += qs * k0.z; acc[ri][3]  += qs * k0.w;
        acc[ri][4]  += qs * k1.x; acc[ri][5]  += qs * k1.y;
        acc[ri][6]  += qs * k1.z; acc[ri][7]  += qs * k1.w;
        acc[ri][8]  += qs * k2.x; acc[ri][9]  += qs * k2.y;
        acc[ri][10] += qs * k2.z; acc[ri][11] += qs * k2.w;
        acc[ri][12] += qs * k3.x; acc[ri][13] += qs * k3.y;
        acc[ri][14] += qs * k3.z; acc[ri][15] += qs * k3.w;
      }
    }
  }

  float* ob = out + (size_t)bh * SEQ * DH + (size_t)(row_base + r0) * DH + c0;
#pragma unroll
  for (int ri = 0; ri < 4; ++ri) {
#pragma unroll
    for (int j = 0; j < 4; ++j) {
      float4 w = {acc[ri][4 * j + 0], acc[ri][4 * j + 1],
                  acc[ri][4 * j + 2], acc[ri][4 * j + 3]};
      *(float4*)&ob[(size_t)ri * 64 * DH + 4 * j] = w;
    }
  }
}

// ---------------------------------------------------------------------------
extern "C" void kernel_launch(void* const* d_in, const int* in_sizes, int n_in,
                              void* d_out, int out_size, void* d_ws, size_t ws_size,
                              hipStream_t stream) {
  const float* q = (const float*)d_in[0];
  const float* k = (const float*)d_in[1];
  const float* v = (const float*)d_in[2];
  float* out = (float*)d_out;

  float* kvf = (float*)d_ws;                      // [BH][64*64] = 1 MB
  float* partial = kvf + (size_t)BH * DH * DH;    // [BH*nchunk][64*64]

  int nchunk = 32;
  const size_t head_mat = (size_t)BH * DH * DH * sizeof(float);  // 1 MB
  while (nchunk > 1 && ws_size < head_mat * (size_t)(nchunk + 1)) nchunk >>= 1;
  int rows = SEQ / nchunk;

  hipLaunchKernelGGL(kv_partial_kernel, dim3(BH * nchunk), dim3(128), 0, stream,
                     k, v, partial, nchunk, rows);
  hipLaunchKernelGGL(kv_reduce_kernel, dim3(256), dim3(256), 0, stream,
                     partial, kvf, nchunk);
  hipLaunchKernelGGL(out_kernel, dim3(BH * 16), dim3(256), 0, stream,
                     q, kvf, out);
}

// Round 6
// 123.557 us; speedup vs baseline: 1.4227x; 1.4227x over previous
//
#include <hip/hip_runtime.h>

#define BH  64
#define SEQ 4096
#define DH  64
#define TILE 16

// ---------------------------------------------------------------------------
// Kernel 1: partial kv = k^T v over a chunk of S rows. One (b,h,chunk)/block.
// 128 threads = 2 waves, thread tile 4(d) x 8(e).
// Double-buffered LDS with async-split staging (T14): issue tile t+1's global
// loads to regs BEFORE computing tile t; write regs->LDS after the barrier.
// LDS 16 KB -> 10 blocks/CU. k/v LDS reads are lane-duplicated -> broadcast.
// ---------------------------------------------------------------------------
__global__ __launch_bounds__(128) void kv_partial_kernel(
    const float* __restrict__ k, const float* __restrict__ v,
    float* __restrict__ partial, int nchunk, int rows_per_chunk) {
  const int t = threadIdx.x;
  const int bh = blockIdx.x / nchunk;
  const int chunk = blockIdx.x - bh * nchunk;

  const float* kb = k + (size_t)bh * SEQ * DH + (size_t)chunk * rows_per_chunk * DH;
  const float* vb = v + (size_t)bh * SEQ * DH + (size_t)chunk * rows_per_chunk * DH;

  __shared__ float ks[2][TILE * 64];   // 4 KB each
  __shared__ float vs[2][TILE * 64];

  const int d0 = (t & 15) * 4;   // 16 d-groups of 4
  const int e0 = (t >> 4) * 8;   // 8 e-groups of 8

  float acc[4][8];
#pragma unroll
  for (int i = 0; i < 4; ++i)
#pragma unroll
    for (int j = 0; j < 8; ++j) acc[i][j] = 0.f;

  // staging registers: per tile 256 float4 per array / 128 thr = 2 each
  float4 krg[2], vrg[2];

  const int ntiles = rows_per_chunk / TILE;

  // prologue: tile 0
  {
    const float4* gk = (const float4*)kb;
    const float4* gv = (const float4*)vb;
    krg[0] = gk[t]; krg[1] = gk[t + 128];
    vrg[0] = gv[t]; vrg[1] = gv[t + 128];
    float4* K4 = (float4*)ks[0];
    float4* V4 = (float4*)vs[0];
    K4[t] = krg[0]; K4[t + 128] = krg[1];
    V4[t] = vrg[0]; V4[t + 128] = vrg[1];
  }
  __syncthreads();

  int cur = 0;
  for (int tt = 0; tt < ntiles; ++tt) {
    // issue next tile's global loads early (latency hides under compute)
    if (tt + 1 < ntiles) {
      const float4* gk = (const float4*)(kb + (size_t)(tt + 1) * TILE * 64);
      const float4* gv = (const float4*)(vb + (size_t)(tt + 1) * TILE * 64);
      krg[0] = gk[t]; krg[1] = gk[t + 128];
      vrg[0] = gv[t]; vrg[1] = gv[t + 128];
    }

    // compute TILE rows from buf[cur]
#pragma unroll
    for (int r = 0; r < TILE; ++r) {
      float4 kav = *(const float4*)&ks[cur][r * 64 + d0];
      float4 v0  = *(const float4*)&vs[cur][r * 64 + e0];
      float4 v1  = *(const float4*)&vs[cur][r * 64 + e0 + 4];
      float ka[4] = {kav.x, kav.y, kav.z, kav.w};
      float va[8] = {v0.x, v0.y, v0.z, v0.w, v1.x, v1.y, v1.z, v1.w};
#pragma unroll
      for (int i = 0; i < 4; ++i)
#pragma unroll
        for (int j = 0; j < 8; ++j) acc[i][j] += ka[i] * va[j];
    }
    __syncthreads();

    // write next tile into the other buffer
    if (tt + 1 < ntiles) {
      float4* K4 = (float4*)ks[cur ^ 1];
      float4* V4 = (float4*)vs[cur ^ 1];
      K4[t] = krg[0]; K4[t + 128] = krg[1];
      V4[t] = vrg[0]; V4[t + 128] = vrg[1];
    }
    __syncthreads();
    cur ^= 1;
  }

  float* pb = partial + (size_t)blockIdx.x * (DH * DH);
#pragma unroll
  for (int i = 0; i < 4; ++i) {
    float4 w0 = {acc[i][0], acc[i][1], acc[i][2], acc[i][3]};
    float4 w1 = {acc[i][4], acc[i][5], acc[i][6], acc[i][7]};
    *(float4*)&pb[(d0 + i) * 64 + e0]     = w0;
    *(float4*)&pb[(d0 + i) * 64 + e0 + 4] = w1;
  }
}

// ---------------------------------------------------------------------------
// Kernel 2: reduce partials -> kvf [BH][64*64]. Fully coalesced float4.
// Grid: 256 blocks x 256 threads covers 65536 float4 slots.
// ---------------------------------------------------------------------------
__global__ __launch_bounds__(256) void kv_reduce_kernel(
    const float* __restrict__ partial, float* __restrict__ kvf, int nchunk) {
  const int gid = blockIdx.x * 256 + threadIdx.x;
  const int bh = gid >> 10;
  const int idx = gid & 1023;
  float4 s = {0.f, 0.f, 0.f, 0.f};
  for (int c = 0; c < nchunk; ++c) {
    const float4* p = (const float4*)(partial + ((size_t)bh * nchunk + c) * (DH * DH));
    float4 x = p[idx];
    s.x += x.x; s.y += x.y; s.z += x.z; s.w += x.w;
  }
  ((float4*)kvf)[gid] = s;
}

// ---------------------------------------------------------------------------
// Kernel 3: out = q @ kv. Block = 64 q-rows (16 KB q footprint -> L1-resident
// across the whole d-loop). Thread = 1 row x 16 cols -> acc 16 VGPR.
// kv staged in LDS; per-d kv row reads are 16-way lane-duplicated ->
// LDS broadcast. Fully unrolled 64-d loop.
// ---------------------------------------------------------------------------
__global__ __launch_bounds__(256) void out_kernel(
    const float* __restrict__ q, const float* __restrict__ kvf,
    float* __restrict__ out) {
  const int t = threadIdx.x;
  const int bh = blockIdx.x >> 6;        // 64 row-blocks per head
  const int rb = blockIdx.x & 63;
  const int row = rb * 64 + (t >> 2);    // 64 rows/block, 4 threads per row
  const int c0 = (t & 3) * 16;

  __shared__ float kv_lds[64 * 64];      // 16 KB

  const float4* gkv4 = (const float4*)(kvf + (size_t)bh * (DH * DH));
  float4* kv4 = (float4*)kv_lds;
#pragma unroll
  for (int j = 0; j < 4; ++j) kv4[t + j * 256] = gkv4[t + j * 256];
  __syncthreads();

  const float* qrow = q + (size_t)bh * SEQ * DH + (size_t)row * DH;

  float acc[16];
#pragma unroll
  for (int j = 0; j < 16; ++j) acc[j] = 0.f;

#pragma unroll
  for (int dc = 0; dc < 8; ++dc) {
    float4 qa = *(const float4*)&qrow[dc * 8];
    float4 qb = *(const float4*)&qrow[dc * 8 + 4];
    float qs[8] = {qa.x, qa.y, qa.z, qa.w, qb.x, qb.y, qb.z, qb.w};
#pragma unroll
    for (int dd = 0; dd < 8; ++dd) {
      const float* kr = &kv_lds[(dc * 8 + dd) * 64 + c0];
      float4 k0 = *(const float4*)&kr[0];
      float4 k1 = *(const float4*)&kr[4];
      float4 k2 = *(const float4*)&kr[8];
      float4 k3 = *(const float4*)&kr[12];
      const float qsv = qs[dd];
      acc[0]  += qsv * k0.x; acc[1]  += qsv * k0.y;
      acc[2]  += qsv * k0.z; acc[3]  += qsv * k0.w;
      acc[4]  += qsv * k1.x; acc[5]  += qsv * k1.y;
      acc[6]  += qsv * k1.z; acc[7]  += qsv * k1.w;
      acc[8]  += qsv * k2.x; acc[9]  += qsv * k2.y;
      acc[10] += qsv * k2.z; acc[11] += qsv * k2.w;
      acc[12] += qsv * k3.x; acc[13] += qsv * k3.y;
      acc[14] += qsv * k3.z; acc[15] += qsv * k3.w;
    }
  }

  float* ob = out + (size_t)bh * SEQ * DH + (size_t)row * DH + c0;
#pragma unroll
  for (int j = 0; j < 4; ++j) {
    float4 w = {acc[4 * j + 0], acc[4 * j + 1], acc[4 * j + 2], acc[4 * j + 3]};
    *(float4*)&ob[4 * j] = w;
  }
}

// ---------------------------------------------------------------------------
extern "C" void kernel_launch(void* const* d_in, const int* in_sizes, int n_in,
                              void* d_out, int out_size, void* d_ws, size_t ws_size,
                              hipStream_t stream) {
  const float* q = (const float*)d_in[0];
  const float* k = (const float*)d_in[1];
  const float* v = (const float*)d_in[2];
  float* out = (float*)d_out;

  float* kvf = (float*)d_ws;                      // [BH][64*64] = 1 MB
  float* partial = kvf + (size_t)BH * DH * DH;    // [BH*nchunk][64*64]

  int nchunk = 32;
  const size_t head_mat = (size_t)BH * DH * DH * sizeof(float);  // 1 MB
  while (nchunk > 1 && ws_size < head_mat * (size_t)(nchunk + 1)) nchunk >>= 1;
  int rows = SEQ / nchunk;

  hipLaunchKernelGGL(kv_partial_kernel, dim3(BH * nchunk), dim3(128), 0, stream,
                     k, v, partial, nchunk, rows);
  hipLaunchKernelGGL(kv_reduce_kernel, dim3(256), dim3(256), 0, stream,
                     partial, kvf, nchunk);
  hipLaunchKernelGGL(out_kernel, dim3(BH * 64), dim3(256), 0, stream,
                     q, kvf, out);
}

// Round 7
// 90.347 us; speedup vs baseline: 1.9456x; 1.3676x over previous
//
#include <hip/hip_runtime.h>

#define BH  64
#define SEQ 4096
#define DH  64
#define KTILE 32
#define NCHUNK 16

// async global->LDS, 16B per lane, wave-uniform LDS base + lane*16 dest
__device__ __forceinline__ void gload_lds16(const float* g, float* l) {
  __builtin_amdgcn_global_load_lds(
      (const __attribute__((address_space(1))) void*)g,
      (__attribute__((address_space(3))) void*)l, 16, 0, 0);
}

// ---------------------------------------------------------------------------
// Kernel 1: partial kv = k^T v over a 256-row chunk. One (b,h,chunk)/block.
// 256 threads = 4 waves; wave w handles tile rows [w*8, w*8+8); each thread
// owns an 8(d) x 8(e) register tile (64 threads of a wave cover 64x64).
// Double-buffered LDS staged via global_load_lds (no VGPR round trip):
//   STAGE(next buf) -> compute(cur) -> vmcnt(0) -> barrier -> flip.
// Cross-wave partial sums reduced through LDS at the end (once).
// LDS 32 KB -> 5 blocks/CU.
// ---------------------------------------------------------------------------
__global__ __launch_bounds__(256) void kv_partial_kernel(
    const float* __restrict__ k, const float* __restrict__ v,
    float* __restrict__ partial, int rows_per_chunk) {
  const int t = threadIdx.x;
  const int bh = blockIdx.x >> 4;            // / NCHUNK
  const int chunk = blockIdx.x & (NCHUNK - 1);

  const float* kb = k + (size_t)bh * SEQ * DH + (size_t)chunk * rows_per_chunk * DH;
  const float* vb = v + (size_t)bh * SEQ * DH + (size_t)chunk * rows_per_chunk * DH;

  __shared__ float smem[8192];   // k buf0 [0,2048) k buf1 [2048,4096) v buf0 [4096,6144) v buf1 [6144,8192)

  const int g    = t & 63;       // lane
  const int grp  = t >> 6;       // wave id 0..3
  const int d0 = (g & 7) * 8;
  const int e0 = (g >> 3) * 8;

  float acc[8][8];
#pragma unroll
  for (int i = 0; i < 8; ++i)
#pragma unroll
    for (int j = 0; j < 8; ++j) acc[i][j] = 0.f;

  const int ntiles = rows_per_chunk / KTILE;   // 8

  // ---- stage tile tt into buffer b (8 KB k + 8 KB v, 4 calls/thread) ----
  auto STAGE = [&](int tt, int b) {
    const float* ksrc = kb + (size_t)tt * KTILE * DH;
    const float* vsrc = vb + (size_t)tt * KTILE * DH;
    float* kd = smem + b * 2048;          // wave-uniform bases
    float* vd = smem + 4096 + b * 2048;
    const int wo = grp * 512;             // wave's 512-float span
    gload_lds16(ksrc + wo + g * 4,       kd + wo);
    gload_lds16(ksrc + wo + 256 + g * 4, kd + wo + 256);
    gload_lds16(vsrc + wo + g * 4,       vd + wo);
    gload_lds16(vsrc + wo + 256 + g * 4, vd + wo + 256);
  };

  STAGE(0, 0);
  asm volatile("s_waitcnt vmcnt(0)" ::: "memory");
  __syncthreads();

  int cur = 0;
  for (int tt = 0; tt < ntiles; ++tt) {
    if (tt + 1 < ntiles) STAGE(tt + 1, cur ^ 1);

    const float* ksb = smem + cur * 2048;
    const float* vsb = smem + 4096 + cur * 2048;
#pragma unroll
    for (int rr = 0; rr < 8; ++rr) {
      const int r = grp * 8 + rr;
      float4 ka0 = *(const float4*)&ksb[r * 64 + d0];
      float4 ka1 = *(const float4*)&ksb[r * 64 + d0 + 4];
      float4 va0 = *(const float4*)&vsb[r * 64 + e0];
      float4 va1 = *(const float4*)&vsb[r * 64 + e0 + 4];
      float kk[8] = {ka0.x, ka0.y, ka0.z, ka0.w, ka1.x, ka1.y, ka1.z, ka1.w};
      float vv[8] = {va0.x, va0.y, va0.z, va0.w, va1.x, va1.y, va1.z, va1.w};
#pragma unroll
      for (int i = 0; i < 8; ++i)
#pragma unroll
        for (int j = 0; j < 8; ++j) acc[i][j] += kk[i] * vv[j];
    }

    asm volatile("s_waitcnt vmcnt(0)" ::: "memory");
    __syncthreads();
    cur ^= 1;
  }

  // ---- cross-wave reduction through LDS (layout [i][g] to avoid 32-way) ----
  // Pass A: waves 2,3 write their acc; waves 0,1 accumulate.
  if (grp >= 2) {
    float* reg = smem + (grp - 2) * 4096;
#pragma unroll
    for (int i = 0; i < 8; ++i) {
      float4 w0 = {acc[i][0], acc[i][1], acc[i][2], acc[i][3]};
      float4 w1 = {acc[i][4], acc[i][5], acc[i][6], acc[i][7]};
      *(float4*)&reg[(2 * i) * 256 + g * 4]     = w0;
      *(float4*)&reg[(2 * i + 1) * 256 + g * 4] = w1;
    }
  }
  __syncthreads();
  if (grp < 2) {
    const float* reg = smem + grp * 4096;
#pragma unroll
    for (int i = 0; i < 8; ++i) {
      float4 a = *(const float4*)&reg[(2 * i) * 256 + g * 4];
      float4 b = *(const float4*)&reg[(2 * i + 1) * 256 + g * 4];
      acc[i][0] += a.x; acc[i][1] += a.y; acc[i][2] += a.z; acc[i][3] += a.w;
      acc[i][4] += b.x; acc[i][5] += b.y; acc[i][6] += b.z; acc[i][7] += b.w;
    }
  }
  __syncthreads();
  // Pass B: wave 1 writes; wave 0 accumulates and stores.
  if (grp == 1) {
#pragma unroll
    for (int i = 0; i < 8; ++i) {
      float4 w0 = {acc[i][0], acc[i][1], acc[i][2], acc[i][3]};
      float4 w1 = {acc[i][4], acc[i][5], acc[i][6], acc[i][7]};
      *(float4*)&smem[(2 * i) * 256 + g * 4]     = w0;
      *(float4*)&smem[(2 * i + 1) * 256 + g * 4] = w1;
    }
  }
  __syncthreads();
  if (grp == 0) {
#pragma unroll
    for (int i = 0; i < 8; ++i) {
      float4 a = *(const float4*)&smem[(2 * i) * 256 + g * 4];
      float4 b = *(const float4*)&smem[(2 * i + 1) * 256 + g * 4];
      acc[i][0] += a.x; acc[i][1] += a.y; acc[i][2] += a.z; acc[i][3] += a.w;
      acc[i][4] += b.x; acc[i][5] += b.y; acc[i][6] += b.z; acc[i][7] += b.w;
    }
    float* pb = partial + (size_t)blockIdx.x * (DH * DH);
#pragma unroll
    for (int i = 0; i < 8; ++i) {
      float4 w0 = {acc[i][0], acc[i][1], acc[i][2], acc[i][3]};
      float4 w1 = {acc[i][4], acc[i][5], acc[i][6], acc[i][7]};
      *(float4*)&pb[(d0 + i) * 64 + e0]     = w0;
      *(float4*)&pb[(d0 + i) * 64 + e0 + 4] = w1;
    }
  }
}

// ---------------------------------------------------------------------------
// Kernel 2: reduce partials -> kvf [BH][64*64]. 256 blocks x 256 threads
// covers 65536 float4 slots.
// ---------------------------------------------------------------------------
__global__ __launch_bounds__(256) void kv_reduce_kernel(
    const float* __restrict__ partial, float* __restrict__ kvf) {
  const int gid = blockIdx.x * 256 + threadIdx.x;
  const int bh = gid >> 10;
  const int idx = gid & 1023;
  float4 s = {0.f, 0.f, 0.f, 0.f};
  for (int c = 0; c < NCHUNK; ++c) {
    const float4* p = (const float4*)(partial + ((size_t)bh * NCHUNK + c) * (DH * DH));
    float4 x = p[idx];
    s.x += x.x; s.y += x.y; s.z += x.z; s.w += x.w;
  }
  ((float4*)kvf)[gid] = s;
}

// ---------------------------------------------------------------------------
// Kernel 3: out = q @ kv. Block = 64 q-rows. Thread = 1 row x 16 cols.
// Entire q row hoisted to registers up front (16 independent dwordx4 issued
// before the barrier -> overlap kv staging latency). kv in LDS, broadcast
// reads. Fully unrolled d-loop.
// ---------------------------------------------------------------------------
__global__ __launch_bounds__(256) void out_kernel(
    const float* __restrict__ q, const float* __restrict__ kvf,
    float* __restrict__ out) {
  const int t = threadIdx.x;
  const int bh = blockIdx.x >> 6;
  const int rb = blockIdx.x & 63;
  const int row = rb * 64 + (t >> 2);
  const int c0 = (t & 3) * 16;

  __shared__ float kv_lds[64 * 64];

  const float4* gkv4 = (const float4*)(kvf + (size_t)bh * (DH * DH));
  float4* kv4 = (float4*)kv_lds;
#pragma unroll
  for (int j = 0; j < 4; ++j) kv4[t + j * 256] = gkv4[t + j * 256];

  // issue all q loads before the barrier
  const float* qrow = q + (size_t)bh * SEQ * DH + (size_t)row * DH;
  float4 qv[16];
#pragma unroll
  for (int i = 0; i < 16; ++i) qv[i] = *(const float4*)&qrow[i * 4];

  __syncthreads();

  float acc[16];
#pragma unroll
  for (int j = 0; j < 16; ++j) acc[j] = 0.f;

#pragma unroll
  for (int dc = 0; dc < 16; ++dc) {
    float qs[4] = {qv[dc].x, qv[dc].y, qv[dc].z, qv[dc].w};
#pragma unroll
    for (int dd = 0; dd < 4; ++dd) {
      const float* kr = &kv_lds[(dc * 4 + dd) * 64 + c0];
      float4 k0 = *(const float4*)&kr[0];
      float4 k1 = *(const float4*)&kr[4];
      float4 k2 = *(const float4*)&kr[8];
      float4 k3 = *(const float4*)&kr[12];
      const float qsv = qs[dd];
      acc[0]  += qsv * k0.x; acc[1]  += qsv * k0.y;
      acc[2]  += qsv * k0.z; acc[3]  += qsv * k0.w;
      acc[4]  += qsv * k1.x; acc[5]  += qsv * k1.y;
      acc[6]  += qsv * k1.z; acc[7]  += qsv * k1.w;
      acc[8]  += qsv * k2.x; acc[9]  += qsv * k2.y;
      acc[10] += qsv * k2.z; acc[11] += qsv * k2.w;
      acc[12] += qsv * k3.x; acc[13] += qsv * k3.y;
      acc[14] += qsv * k3.z; acc[15] += qsv * k3.w;
    }
  }

  float* ob = out + (size_t)bh * SEQ * DH + (size_t)row * DH + c0;
#pragma unroll
  for (int j = 0; j < 4; ++j) {
    float4 w = {acc[4 * j + 0], acc[4 * j + 1], acc[4 * j + 2], acc[4 * j + 3]};
    *(float4*)&ob[4 * j] = w;
  }
}

// ---------------------------------------------------------------------------
extern "C" void kernel_launch(void* const* d_in, const int* in_sizes, int n_in,
                              void* d_out, int out_size, void* d_ws, size_t ws_size,
                              hipStream_t stream) {
  const float* q = (const float*)d_in[0];
  const float* k = (const float*)d_in[1];
  const float* v = (const float*)d_in[2];
  float* out = (float*)d_out;

  float* kvf = (float*)d_ws;                      // [BH][64*64] = 1 MB
  float* partial = kvf + (size_t)BH * DH * DH;    // [BH*NCHUNK][64*64] = 16 MB

  const int rows = SEQ / NCHUNK;                  // 256

  hipLaunchKernelGGL(kv_partial_kernel, dim3(BH * NCHUNK), dim3(256), 0, stream,
                     k, v, partial, rows);
  hipLaunchKernelGGL(kv_reduce_kernel, dim3(256), dim3(256), 0, stream,
                     partial, kvf);
  hipLaunchKernelGGL(out_kernel, dim3(BH * 64), dim3(256), 0, stream,
                     q, kvf, out);
}